// Round 3
// baseline (796.158 us; speedup 1.0000x reference)
//
#include <hip/hip_runtime.h>
#include <hip/hip_bf16.h>
#include <stdint.h>

#define D_IN   4096
#define D_OUT  4096
#define MROWS  8192   // B*S = 4*2048
#define CAPN   1024
#define KITERS (D_IN / 32)   // 128

typedef __bf16 bf16x8 __attribute__((ext_vector_type(8)));
typedef float f32x4 __attribute__((ext_vector_type(4)));

// wait until <=4 of this wave's global_load_lds remain, then barrier.
// (next tile's 4 loads stay in flight ACROSS the barrier - the key trick.)
#define WAITBAR4 asm volatile("s_waitcnt vmcnt(4)\n\ts_barrier" ::: "memory")
#define WAITBAR0 asm volatile("s_waitcnt vmcnt(0)\n\ts_barrier" ::: "memory")

// ---------- async global->LDS (16B/lane, uniform LDS base) ----------
__device__ static inline void async_copy16(const void* g, void* l) {
  __builtin_amdgcn_global_load_lds((__attribute__((address_space(1))) void*)g,
                                   (__attribute__((address_space(3))) void*)l,
                                   16, 0, 0);
}

// ---------- fused x->bf16 and dequant W->bf16 ----------
__global__ __launch_bounds__(256) void cvt_kernel(const float* __restrict__ x,
                                                  const float* __restrict__ wl,
                                                  const float* __restrict__ wscale,
                                                  __hip_bfloat16* __restrict__ xb,
                                                  __hip_bfloat16* __restrict__ wb) {
  int bid = blockIdx.x;
  if (bid < (MROWS * D_IN) / 2048) {
    size_t i = ((size_t)bid * 256 + threadIdx.x) * 8;
    float4 f0 = *(const float4*)(x + i);
    float4 f1 = *(const float4*)(x + i + 4);
    union { __hip_bfloat16 h[8]; uint4 u; } o;
    o.h[0] = __float2bfloat16(f0.x); o.h[1] = __float2bfloat16(f0.y);
    o.h[2] = __float2bfloat16(f0.z); o.h[3] = __float2bfloat16(f0.w);
    o.h[4] = __float2bfloat16(f1.x); o.h[5] = __float2bfloat16(f1.y);
    o.h[6] = __float2bfloat16(f1.z); o.h[7] = __float2bfloat16(f1.w);
    *(uint4*)(xb + i) = o.u;
  } else {
    size_t i = ((size_t)(bid - (MROWS * D_IN) / 2048) * 256 + threadIdx.x) * 8;
    int row = (int)(i >> 12);           // D_IN = 4096 per row
    float s = wscale[row];
    float4 f0 = *(const float4*)(wl + i);
    float4 f1 = *(const float4*)(wl + i + 4);
    union { __hip_bfloat16 h[8]; uint4 u; } o;
    o.h[0] = __float2bfloat16(f0.x * s); o.h[1] = __float2bfloat16(f0.y * s);
    o.h[2] = __float2bfloat16(f0.z * s); o.h[3] = __float2bfloat16(f0.w * s);
    o.h[4] = __float2bfloat16(f1.x * s); o.h[5] = __float2bfloat16(f1.y * s);
    o.h[6] = __float2bfloat16(f1.z * s); o.h[7] = __float2bfloat16(f1.w * s);
    *(uint4*)(wb + i) = o.u;
  }
}

// ---------- logits[c] = mem_keys[c,:] . q  (q = x[0,0,:], fp32) ----------
__global__ __launch_bounds__(256) void mem_logits_kernel(const float* __restrict__ keys,
                                                         const float* __restrict__ q,
                                                         float* __restrict__ logits) {
  int c = blockIdx.x;
  const float* k = keys + (size_t)c * D_IN;
  float p = 0.f;
  for (int i = threadIdx.x; i < D_IN; i += 256) p += k[i] * q[i];
  for (int off = 32; off; off >>= 1) p += __shfl_down(p, off);
  __shared__ float r[4];
  if ((threadIdx.x & 63) == 0) r[threadIdx.x >> 6] = p;
  __syncthreads();
  if (threadIdx.x == 0) logits[c] = r[0] + r[1] + r[2] + r[3];
}

// ---------- fused softmax + memory_out ----------
// 64 blocks x 256 thr; each block recomputes the softmax stats (4KB logits,
// L2-hit) then produces memo[o] for its 64-wide o-chunk. No atomics/memset.
__global__ __launch_bounds__(256) void softmax_memout_kernel(const float* __restrict__ logits,
                                                             const float* __restrict__ vals,
                                                             float* __restrict__ memo) {
  __shared__ float sl[CAPN];
  __shared__ float wred[16];
  __shared__ float sM, sS;
  __shared__ float red[4][64];
  const int t = threadIdx.x;

  float4 v = ((const float4*)logits)[t];             // 256*4 = 1024 logits
  float m = fmaxf(fmaxf(v.x, v.y), fmaxf(v.z, v.w));
  for (int off = 32; off; off >>= 1) m = fmaxf(m, __shfl_down(m, off));
  if ((t & 63) == 0) wred[t >> 6] = m;
  __syncthreads();
  if (t == 0) sM = fmaxf(fmaxf(wred[0], wred[1]), fmaxf(wred[2], wred[3]));
  __syncthreads();
  float M = sM;
  float e0 = __expf(v.x - M), e1 = __expf(v.y - M),
        e2 = __expf(v.z - M), e3 = __expf(v.w - M);
  sl[4 * t + 0] = e0; sl[4 * t + 1] = e1; sl[4 * t + 2] = e2; sl[4 * t + 3] = e3;
  float s = e0 + e1 + e2 + e3;
  for (int off = 32; off; off >>= 1) s += __shfl_down(s, off);
  if ((t & 63) == 0) wred[4 + (t >> 6)] = s;
  __syncthreads();
  if (t == 0) sS = wred[4] + wred[5] + wred[6] + wred[7];
  __syncthreads();

  const int ol = t & 63;            // o lane
  const int cl = t >> 6;            // c group (4-way split of CAP)
  const int o = blockIdx.x * 64 + ol;
  float acc = 0.f;
#pragma unroll 8
  for (int c = cl; c < CAPN; c += 4) acc += sl[c] * vals[(size_t)c * D_OUT + o];
  red[cl][ol] = acc;
  __syncthreads();
  if (cl == 0) memo[o] = (red[0][ol] + red[1][ol] + red[2][ol] + red[3][ol]) / sS;
}

// ---------- GEMM helpers ----------
__device__ __forceinline__ void stage_tile(const __hip_bfloat16* gA0, const __hip_bfloat16* gA1,
                                           const __hip_bfloat16* gB0, const __hip_bfloat16* gB1,
                                           int koff, bf16x8* As, bf16x8* Bs, int w) {
  async_copy16(gA0 + koff, &As[w * 64]);
  async_copy16(gA1 + koff, &As[(w + 4) * 64]);
  async_copy16(gB0 + koff, &Bs[w * 64]);
  async_copy16(gB1 + koff, &Bs[(w + 4) * 64]);
}

__device__ __forceinline__ void compute_tile(const bf16x8* As, const bf16x8* Bs,
                                             int wm, int wn, int l, f32x4 acc[4][4]) {
  bf16x8 a[4], b[4];
#pragma unroll
  for (int i = 0; i < 4; i++) a[i] = As[(wm + i) * 64 + l];
#pragma unroll
  for (int j = 0; j < 4; j++) b[j] = Bs[(wn + j) * 64 + l];
#pragma unroll
  for (int i = 0; i < 4; i++)
#pragma unroll
    for (int j = 0; j < 4; j++)
      acc[i][j] = __builtin_amdgcn_mfma_f32_16x16x32_bf16(a[i], b[j], acc[i][j], 0, 0, 0);
}

// ---------- main GEMM: C[m][n] = sum_k A[m][k]*W[n][k] + 0.01*memo[n] ----------
// 128x128 tile, BK=32, 4 waves (2x2), 16x16x32 bf16 MFMA, global_load_lds w16.
// THREE LDS buffers, loads issued 2 iterations ahead, barrier waits vmcnt(4)
// (not 0) so the next tile's DMA stays in flight across the barrier.
__global__ __launch_bounds__(256) void gemm_bt_kernel(const __hip_bfloat16* __restrict__ A,
                                                      const __hip_bfloat16* __restrict__ Bm,
                                                      const float* __restrict__ memo,
                                                      float* __restrict__ C) {
  __shared__ bf16x8 As[3][512];   // per buf: 8 m-tiles x 64 frags (frag=[kq(4)][m(16)])
  __shared__ bf16x8 Bs[3][512];
  const int tid = threadIdx.x;
  const int l = tid & 63;
  const int w = tid >> 6;
  const int m_blk = blockIdx.y * 128;
  const int n_blk = blockIdx.x * 128;

  const int lm = l & 15;          // row within 16-row tile for staging
  const int lk = (l >> 4) * 8;    // k offset for staging (0,8,16,24)

  const __hip_bfloat16* gA0 = A  + (size_t)(m_blk + w * 16 + lm) * D_IN + lk;
  const __hip_bfloat16* gA1 = gA0 + (size_t)64 * D_IN;
  const __hip_bfloat16* gB0 = Bm + (size_t)(n_blk + w * 16 + lm) * D_IN + lk;
  const __hip_bfloat16* gB1 = gB0 + (size_t)64 * D_IN;

  const int wm = (w >> 1) * 4;    // wave's m-tile base (compute)
  const int wn = (w & 1) * 4;     // wave's n-tile base (compute)

  // prologue: stage tiles 0 and 1
  stage_tile(gA0, gA1, gB0, gB1, 0,  As[0], Bs[0], w);
  stage_tile(gA0, gA1, gB0, gB1, 32, As[1], Bs[1], w);

  f32x4 acc[4][4] = {};

  // main loop: k = 0..125 in groups of 3 (constant buffer indices)
  int koff = 64;                   // element offset of tile k+2 at group start
  for (int g = 0; g < 42; ++g) {
    WAITBAR4;                                              // tile 3g ready; 3g+1 in flight
    stage_tile(gA0, gA1, gB0, gB1, koff,      As[2], Bs[2], w);
    compute_tile(As[0], Bs[0], wm, wn, l, acc);
    WAITBAR4;
    stage_tile(gA0, gA1, gB0, gB1, koff + 32, As[0], Bs[0], w);
    compute_tile(As[1], Bs[1], wm, wn, l, acc);
    WAITBAR4;
    stage_tile(gA0, gA1, gB0, gB1, koff + 64, As[1], Bs[1], w);
    compute_tile(As[2], Bs[2], wm, wn, l, acc);
    koff += 96;
  }
  // peeled iterations k=126 (buf0), k=127 (buf1)
  WAITBAR4;
  compute_tile(As[0], Bs[0], wm, wn, l, acc);
  WAITBAR0;
  compute_tile(As[1], Bs[1], wm, wn, l, acc);

  // epilogue: D mapping col = l&15, row = (l>>4)*4 + r
  const int col_l = l & 15;
  const int row_l = (l >> 4) * 4;
#pragma unroll
  for (int j = 0; j < 4; j++) {
    int col = n_blk + (wn + j) * 16 + col_l;
    float mo = 0.01f * memo[col];
#pragma unroll
    for (int i = 0; i < 4; i++) {
      int row = m_blk + (wm + i) * 16 + row_l;
      float* cp = C + (size_t)row * D_OUT + col;
#pragma unroll
      for (int r = 0; r < 4; r++) cp[(size_t)r * D_OUT] = acc[i][j][r] + mo;
    }
  }
}

extern "C" void kernel_launch(void* const* d_in, const int* in_sizes, int n_in,
                              void* d_out, int out_size, void* d_ws, size_t ws_size,
                              hipStream_t stream) {
  const float* x   = (const float*)d_in[0];   // [4,2048,4096]
  const float* wl  = (const float*)d_in[1];   // [4096,4096]
  const float* wsc = (const float*)d_in[2];   // [4096,1]
  const float* mk  = (const float*)d_in[3];   // [1024,4096]
  const float* mv  = (const float*)d_in[4];   // [1024,4096]
  float* out = (float*)d_out;                 // [4,2048,4096] fp32

  char* wsb = (char*)d_ws;
  __hip_bfloat16* xb = (__hip_bfloat16*)wsb;                                    // 67,108,864 B
  __hip_bfloat16* wb = (__hip_bfloat16*)(wsb + (size_t)MROWS * D_IN * 2);       // 33,554,432 B
  float* logits = (float*)(wsb + (size_t)MROWS * D_IN * 2 + (size_t)D_OUT * D_IN * 2);
  float* memo = logits + CAPN;                                                  // 4096 floats

  // fused conversions (x -> bf16, W dequant -> bf16)
  cvt_kernel<<<dim3((MROWS * D_IN) / 2048 + (D_OUT * D_IN) / 2048), dim3(256), 0, stream>>>(
      x, wl, wsc, xb, wb);

  // associative-memory path (q = x[0,0,:], fp32 throughout)
  mem_logits_kernel<<<dim3(CAPN), dim3(256), 0, stream>>>(mk, x, logits);
  softmax_memout_kernel<<<dim3(D_OUT / 64), dim3(256), 0, stream>>>(logits, mv, memo);

  // main GEMM + fused memory_out epilogue
  gemm_bt_kernel<<<dim3(D_OUT / 128, MROWS / 128), dim3(256), 0, stream>>>(xb, wb, memo, out);
}